// Round 1
// baseline (160.477 us; speedup 1.0000x reference)
//
#include <hip/hip_runtime.h>
#include <hip/hip_bf16.h>

#define B_ROWS 4096
#define N2     8192
#define DIM    128
#define INV_T  2.0f   // 1/TEMPERATURE

typedef __attribute__((ext_vector_type(8))) short bf16x8;
typedef __attribute__((ext_vector_type(4))) float f32x4;

__device__ __forceinline__ unsigned short f2bf(float f) {
    union { float f; unsigned int u; } v; v.f = f;
    unsigned int u = v.u;
    // round-to-nearest-even bf16
    unsigned int r = (u + 0x7fffu + ((u >> 16) & 1u)) >> 16;
    return (unsigned short)r;
}

// Kernel 1: one wave per row -> L2-normalize, write bf16; also zero rowsum.
__global__ __launch_bounds__(256) void nk_normalize(
        const float* __restrict__ zi, const float* __restrict__ zj,
        unsigned short* __restrict__ rn, float* __restrict__ rowsum) {
    int gtid = blockIdx.x * 256 + threadIdx.x;
    if (gtid < N2) rowsum[gtid] = 0.0f;
    int row  = gtid >> 6;
    int lane = threadIdx.x & 63;
    const float* src = (row < B_ROWS) ? (zi + (size_t)row * DIM)
                                      : (zj + (size_t)(row - B_ROWS) * DIM);
    float2 v = reinterpret_cast<const float2*>(src)[lane];
    float ss = v.x * v.x + v.y * v.y;
#pragma unroll
    for (int m = 1; m < 64; m <<= 1) ss += __shfl_xor(ss, m);
    float scale = 1.0f / fmaxf(sqrtf(ss), 1e-8f);
    ushort2 o;
    o.x = f2bf(v.x * scale);
    o.y = f2bf(v.y * scale);
    reinterpret_cast<ushort2*>(rn + (size_t)row * DIM)[lane] = o;
}

// Kernel 2: sim = RN * RN^T via MFMA, fused exp-sum epilogue.
// Block = 256 threads = 4 waves, 2x2 wave arrangement -> 128x128 block tile.
// Each wave: 64x64 output tile = 4x4 subtiles of 16x16, K=128 in 4 steps of 32.
__global__ __launch_bounds__(256) void nk_simloss(
        const unsigned short* __restrict__ rn,
        float* __restrict__ rowsum, float* __restrict__ pos) {
    int bi   = blockIdx.x >> 6;
    int bj   = blockIdx.x & 63;
    int wid  = threadIdx.x >> 6;
    int lane = threadIdx.x & 63;
    int i0 = bi * 128 + (wid >> 1) * 64;
    int j0 = bj * 128 + (wid & 1) * 64;
    int lc = lane & 15;   // fragment col / row-in-16
    int lg = lane >> 4;   // k-group

    // A-frag lane l: RN[i0+mi*16 + (l&15)][ks*32 + (l>>4)*8 + e]
    // B-frag lane l: RN[j0+nj*16 + (l&15)][ks*32 + (l>>4)*8 + e]   (B = RN^T)
    const unsigned short* abase = rn + (size_t)(i0 + lc) * DIM + lg * 8;
    const unsigned short* bbase = rn + (size_t)(j0 + lc) * DIM + lg * 8;

    f32x4 acc[4][4];
#pragma unroll
    for (int mi = 0; mi < 4; ++mi)
#pragma unroll
        for (int nj = 0; nj < 4; ++nj)
            acc[mi][nj] = (f32x4){0.f, 0.f, 0.f, 0.f};

#pragma unroll
    for (int ks = 0; ks < 4; ++ks) {
        bf16x8 af[4], bfr[4];
#pragma unroll
        for (int mi = 0; mi < 4; ++mi)
            af[mi] = *reinterpret_cast<const bf16x8*>(abase + (size_t)mi * 16 * DIM + ks * 32);
#pragma unroll
        for (int nj = 0; nj < 4; ++nj)
            bfr[nj] = *reinterpret_cast<const bf16x8*>(bbase + (size_t)nj * 16 * DIM + ks * 32);
#pragma unroll
        for (int mi = 0; mi < 4; ++mi)
#pragma unroll
            for (int nj = 0; nj < 4; ++nj)
                acc[mi][nj] = __builtin_amdgcn_mfma_f32_16x16x32_bf16(
                    af[mi], bfr[nj], acc[mi][nj], 0, 0, 0);
    }

    // Epilogue: C/D layout (16x16x32): col = lane&15, row = (lane>>4)*4 + p.
    // exp(sim/T), mask self-diagonal, capture pos at gj == gi^4096,
    // 16-lane reduce per row, one atomicAdd per row.
#pragma unroll
    for (int mi = 0; mi < 4; ++mi) {
#pragma unroll
        for (int p = 0; p < 4; ++p) {
            int gi = i0 + mi * 16 + lg * 4 + p;
            float part = 0.f;
#pragma unroll
            for (int nj = 0; nj < 4; ++nj) {
                float s  = acc[mi][nj][p];
                int   gj = j0 + nj * 16 + lc;
                float e  = __expf(s * INV_T);
                if (gj == gi) e = 0.f;                    // exclude self
                if (gj == (gi ^ B_ROWS)) pos[gi] = s;     // positive pair
                part += e;
            }
#pragma unroll
            for (int m = 1; m < 16; m <<= 1) part += __shfl_xor(part, m);
            if (lc == 0) atomicAdd(&rowsum[gi], part);
        }
    }
}

// Kernel 3: loss = sum_i (log(rowsum_i) - pos_i/T) / N2
__global__ __launch_bounds__(256) void nk_finalize(
        const float* __restrict__ rowsum, const float* __restrict__ pos,
        float* __restrict__ out) {
    __shared__ float red[256];
    float s = 0.f;
    for (int i = threadIdx.x; i < N2; i += 256)
        s += logf(rowsum[i]) - pos[i] * INV_T;
    red[threadIdx.x] = s;
    __syncthreads();
    for (int off = 128; off > 0; off >>= 1) {
        if (threadIdx.x < off) red[threadIdx.x] += red[threadIdx.x + off];
        __syncthreads();
    }
    if (threadIdx.x == 0) out[0] = red[0] / (float)N2;
}

extern "C" void kernel_launch(void* const* d_in, const int* in_sizes, int n_in,
                              void* d_out, int out_size, void* d_ws, size_t ws_size,
                              hipStream_t stream) {
    const float* zi = (const float*)d_in[0];
    const float* zj = (const float*)d_in[1];
    float* out = (float*)d_out;

    unsigned short* rn = (unsigned short*)d_ws;                       // 8192*128*2B = 2 MiB
    float* rowsum = (float*)((char*)d_ws + (size_t)N2 * DIM * 2);     // 32 KiB
    float* pos    = rowsum + N2;                                      // 32 KiB

    nk_normalize<<<(N2 * 64) / 256, 256, 0, stream>>>(zi, zj, rn, rowsum);
    nk_simloss<<<64 * 64, 256, 0, stream>>>(rn, rowsum, pos);
    nk_finalize<<<1, 256, 0, stream>>>(rowsum, pos, out);
}

// Round 2
// 133.814 us; speedup vs baseline: 1.1993x; 1.1993x over previous
//
#include <hip/hip_runtime.h>
#include <hip/hip_bf16.h>

#define B_ROWS 4096
#define N2     8192
#define DIM    128
#define INV_T  2.0f
#define C_LSE  2.8853900817779268f   // (1/T) * log2(e)
#define LN2    0.6931471805599453f

typedef __attribute__((ext_vector_type(8))) short bf16x8;
typedef __attribute__((ext_vector_type(4))) float f32x4;

#if __has_builtin(__builtin_amdgcn_exp2f)
#define EXP2F(x) __builtin_amdgcn_exp2f(x)
#else
#define EXP2F(x) exp2f(x)
#endif
#if __has_builtin(__builtin_amdgcn_logf)
#define LOG2F_FAST(x) __builtin_amdgcn_logf(x)
#else
#define LOG2F_FAST(x) log2f(x)
#endif

static __device__ __forceinline__ unsigned short f2bf(float f) {
    union { float f; unsigned int u; } v; v.f = f;
    unsigned int u = v.u;
    return (unsigned short)((u + 0x7fffu + ((u >> 16) & 1u)) >> 16);
}
static __device__ __forceinline__ float bf2f(unsigned short s) {
    union { unsigned int u; float f; } v; v.u = ((unsigned int)s) << 16;
    return v.f;
}

// K1: one wave per row -> L2-normalize -> bf16; also selfdot (bf16 self-sim) and rowsum=0.
__global__ __launch_bounds__(256) void nk_normalize(
        const float* __restrict__ zi, const float* __restrict__ zj,
        unsigned short* __restrict__ rn, float* __restrict__ rowsum,
        float* __restrict__ selfdot) {
    int gtid = blockIdx.x * 256 + threadIdx.x;
    if (gtid < N2) rowsum[gtid] = 0.0f;
    int row  = gtid >> 6;
    int lane = threadIdx.x & 63;
    const float* src = (row < B_ROWS) ? (zi + (size_t)row * DIM)
                                      : (zj + (size_t)(row - B_ROWS) * DIM);
    float2 v = reinterpret_cast<const float2*>(src)[lane];
    float ss = v.x * v.x + v.y * v.y;
#pragma unroll
    for (int m = 1; m < 64; m <<= 1) ss += __shfl_xor(ss, m);
    float scale = 1.0f / fmaxf(sqrtf(ss), 1e-8f);
    ushort2 o;
    o.x = f2bf(v.x * scale);
    o.y = f2bf(v.y * scale);
    reinterpret_cast<ushort2*>(rn + (size_t)row * DIM)[lane] = o;
    float a = bf2f(o.x), b = bf2f(o.y);
    float sd = a * a + b * b;
#pragma unroll
    for (int m = 1; m < 64; m <<= 1) sd += __shfl_xor(sd, m);
    if (lane == 0) selfdot[row] = sd;
}

// K2: rowsum_i += sum_j exp(2*sim_ij) over this block's column chunk (diag INCLUDED;
// corrected in finalize). Branchless. 1024 blocks = 64 row-panels x 16 col-chunks.
// 4 waves stacked: wave owns 32 rows x 512 cols. A frags persistent in registers.
__global__ __launch_bounds__(256) void nk_simloss(
        const unsigned short* __restrict__ rn, float* __restrict__ rowsum) {
    int bi = blockIdx.x >> 4;   // row panel 0..63
    int bc = blockIdx.x & 15;   // col chunk 0..15
    int wid  = threadIdx.x >> 6;
    int lane = threadIdx.x & 63;
    int lc = lane & 15, lg = lane >> 4;
    int i0 = bi * 128 + wid * 32;

    const unsigned short* abase = rn + (size_t)(i0 + lc) * DIM + lg * 8;
    bf16x8 af[2][4];
#pragma unroll
    for (int mi = 0; mi < 2; ++mi)
#pragma unroll
        for (int ks = 0; ks < 4; ++ks)
            af[mi][ks] = *reinterpret_cast<const bf16x8*>(abase + (size_t)mi * 16 * DIM + ks * 32);

    float part[2][4] = {{0.f, 0.f, 0.f, 0.f}, {0.f, 0.f, 0.f, 0.f}};
    const unsigned short* bbase0 = rn + (size_t)(bc * 512 + lc) * DIM + lg * 8;

#pragma unroll 2
    for (int t = 0; t < 8; ++t) {
        const unsigned short* bbase = bbase0 + (size_t)t * 64 * DIM;
        f32x4 acc[2][4];
#pragma unroll
        for (int mi = 0; mi < 2; ++mi)
#pragma unroll
            for (int nj = 0; nj < 4; ++nj)
                acc[mi][nj] = (f32x4){0.f, 0.f, 0.f, 0.f};
#pragma unroll
        for (int ks = 0; ks < 4; ++ks) {
            bf16x8 bfr[4];
#pragma unroll
            for (int nj = 0; nj < 4; ++nj)
                bfr[nj] = *reinterpret_cast<const bf16x8*>(bbase + (size_t)nj * 16 * DIM + ks * 32);
#pragma unroll
            for (int mi = 0; mi < 2; ++mi)
#pragma unroll
                for (int nj = 0; nj < 4; ++nj)
                    acc[mi][nj] = __builtin_amdgcn_mfma_f32_16x16x32_bf16(
                        af[mi][ks], bfr[nj], acc[mi][nj], 0, 0, 0);
        }
#pragma unroll
        for (int mi = 0; mi < 2; ++mi)
#pragma unroll
            for (int nj = 0; nj < 4; ++nj)
#pragma unroll
                for (int p = 0; p < 4; ++p)
                    part[mi][p] += EXP2F(acc[mi][nj][p] * C_LSE);
    }
    // reduce across the 16 lanes (lc) of each lg-group, then one atomic per row
#pragma unroll
    for (int mi = 0; mi < 2; ++mi)
#pragma unroll
        for (int p = 0; p < 4; ++p) {
            float v = part[mi][p];
#pragma unroll
            for (int m = 1; m < 16; m <<= 1) v += __shfl_xor(v, m);
            if (lc == 0) atomicAdd(&rowsum[i0 + mi * 16 + lg * 4 + p], v);
        }
}

// K3: loss = sum_i [ log(rowsum_i - exp(2*selfdot_i)) - 2*pos_i ] / N2,
// pos_i = <rn_i, rn_{i^B}> recomputed directly (tiny). 128 blocks.
__global__ __launch_bounds__(256) void nk_finalize(
        const unsigned short* __restrict__ rn, const float* __restrict__ rowsum,
        const float* __restrict__ selfdot, float* __restrict__ out) {
    int wid = threadIdx.x >> 6, lane = threadIdx.x & 63;
    int lc = lane & 15, lg = lane >> 4;
    int wavegid = blockIdx.x * 4 + wid;   // 0..511
    float acc = 0.f;
    for (int base = wavegid * 4; base < N2; base += 512 * 4) {
        int row = base + lg;
        bf16x8 a = *reinterpret_cast<const bf16x8*>(rn + (size_t)row * DIM + lc * 8);
        bf16x8 b = *reinterpret_cast<const bf16x8*>(rn + (size_t)(row ^ B_ROWS) * DIM + lc * 8);
        float d = 0.f;
#pragma unroll
        for (int e = 0; e < 8; ++e)
            d += bf2f((unsigned short)a[e]) * bf2f((unsigned short)b[e]);
#pragma unroll
        for (int m = 1; m < 16; m <<= 1) d += __shfl_xor(d, m);
        if (lc == 0) {
            float rs = rowsum[row] - EXP2F(selfdot[row] * C_LSE);
            acc += LOG2F_FAST(rs) * LN2 - INV_T * d;
        }
    }
#pragma unroll
    for (int m = 1; m < 64; m <<= 1) acc += __shfl_xor(acc, m);
    if (lane == 0) atomicAdd(out, acc / (float)N2);
}

extern "C" void kernel_launch(void* const* d_in, const int* in_sizes, int n_in,
                              void* d_out, int out_size, void* d_ws, size_t ws_size,
                              hipStream_t stream) {
    const float* zi = (const float*)d_in[0];
    const float* zj = (const float*)d_in[1];
    float* out = (float*)d_out;

    unsigned short* rn = (unsigned short*)d_ws;                    // 2 MiB
    float* rowsum  = (float*)((char*)d_ws + (size_t)N2 * DIM * 2); // 32 KiB
    float* selfdot = rowsum + N2;                                  // 32 KiB

    hipMemsetAsync(d_out, 0, sizeof(float), stream);
    nk_normalize<<<2048, 256, 0, stream>>>(zi, zj, rn, rowsum, selfdot);
    nk_simloss<<<1024, 256, 0, stream>>>(rn, rowsum);
    nk_finalize<<<128, 256, 0, stream>>>(rn, rowsum, selfdot, out);
}